// Round 4
// baseline (118.603 us; speedup 1.0000x reference)
//
#include <hip/hip_runtime.h>
#include <hip/hip_bf16.h>
#include <stdint.h>

typedef __attribute__((ext_vector_type(4))) float f32x4;
typedef __attribute__((ext_vector_type(8))) short s16x8;

__device__ inline short f2bf(float f) {
  union { float f; uint32_t u; } v; v.f = f;
  uint32_t r = v.u + 0x7fffu + ((v.u >> 16) & 1u);  // RNE
  return (short)(r >> 16);
}

__device__ inline void gload_lds16(const void* g, void* l) {
  __builtin_amdgcn_global_load_lds((const __attribute__((address_space(1))) void*)g,
                                   (__attribute__((address_space(3))) void*)l,
                                   16, 0, 0);
}

#define MFMA16 __builtin_amdgcn_mfma_f32_16x16x32_bf16

// ---------------- Kernel 1: X fp32 -> bf16 ----------------
__global__ __launch_bounds__(256) void k_convert_x(const float* __restrict__ x,
                                                   short* __restrict__ xb) {
  int i = (blockIdx.x * 256 + threadIdx.x) * 8;
  const float4* p = (const float4*)(x + i);
  float4 a = p[0], b = p[1];
  s16x8 o;
  o[0] = f2bf(a.x); o[1] = f2bf(a.y); o[2] = f2bf(a.z); o[3] = f2bf(a.w);
  o[4] = f2bf(b.x); o[5] = f2bf(b.y); o[6] = f2bf(b.z); o[7] = f2bf(b.w);
  *(s16x8*)(xb + i) = o;
}

// ---------------- Kernel 2: W [K=1024][N=1024] fp32 -> Wt [3][N][K] bf16 ----------------
__global__ __launch_bounds__(256) void k_transpose_w(const float* __restrict__ qw,
                                                     const float* __restrict__ kw,
                                                     const float* __restrict__ vw,
                                                     short* __restrict__ wt) {
  __shared__ float tile[64][65];
  int a  = blockIdx.x >> 8;
  int t2 = blockIdx.x & 255;
  int k0 = (t2 >> 4) << 6;
  int n0 = (t2 & 15) << 6;
  const float* w = (a == 0) ? qw : (a == 1) ? kw : vw;
  int c = threadIdx.x & 63, rr = threadIdx.x >> 6;
#pragma unroll
  for (int i = 0; i < 16; ++i) {
    int r = i * 4 + rr;
    tile[r][c] = w[(k0 + r) * 1024 + n0 + c];
  }
  __syncthreads();
  short* o = wt + a * 1048576;
#pragma unroll
  for (int i = 0; i < 16; ++i) {
    int r = i * 4 + rr;
    o[(n0 + r) * 1024 + k0 + c] = f2bf(tile[c][r]);
  }
}

// ---------------- Kernel 3: QKV GEMM — 8-wave, 1 block/CU, counted-vmcnt pipeline ----
// C[8192][3072] = Xb[8192][1024] * Wt^T + bias(applied here), bf16 out.
// BM=256 BN=192 BK=64; 512 thr = 8 waves (2M x 4N), per-wave 128x48 (8x3 frags).
// LDS: A 3 slots x 32KB @0 (staged 2 ahead), B 2 slots x 24KB @98304 (1 ahead) = 144KB.
// Ledger: iter i waits vmcnt(4) -> drains B(i),A(i), leaves A(i+1) in flight.
__global__ __launch_bounds__(512, 2) void k_gemm(const short* __restrict__ xb,
                                                 const short* __restrict__ wt,
                                                 const float* __restrict__ bias3,
                                                 short* __restrict__ C) {
  __shared__ short lds[73728];  // 144 KB
  const int tid = threadIdx.x, lane = tid & 63, wv = tid >> 6;
  const int wm = wv >> 2, wn = wv & 3;
  int wg = blockIdx.x;
  wg = (wg & 7) * 64 + (wg >> 3);  // bijective XCD swizzle (512 = 8*64)
  const int mt = wg >> 4, nt = wg & 15;
  const short* asrc = xb + (size_t)(mt * 256) * 1024;
  const short* bsrc = wt + (size_t)(nt * 192) * 1024;

  // staging source offsets (pre-permuted so LDS dest is linear; slot s stored at ss=s^(r&7))
  int srcA[4], srcB[3];
#pragma unroll
  for (int i = 0; i < 4; ++i) {
    int c = i * 512 + tid, r = c >> 3, ss = c & 7;
    srcA[i] = r * 1024 + (ss ^ (r & 7)) * 8;
  }
#pragma unroll
  for (int i = 0; i < 3; ++i) {
    int c = i * 512 + tid, r = c >> 3, ss = c & 7;
    srcB[i] = r * 1024 + (ss ^ (r & 7)) * 8;
  }
  // fragment read byte-offsets (ks=0); ks=1 -> ^64 (slot+4 == byte^64 under the XOR map)
  int aoff[8], boff[3];
#pragma unroll
  for (int m = 0; m < 8; ++m) {
    int r = wm * 128 + m * 16 + (lane & 15);
    aoff[m] = r * 128 + (((lane >> 4) ^ (r & 7)) << 4);
  }
#pragma unroll
  for (int n = 0; n < 3; ++n) {
    int r = wn * 48 + n * 16 + (lane & 15);
    boff[n] = r * 128 + (((lane >> 4) ^ (r & 7)) << 4);
  }

  f32x4 acc[8][3] = {};

  auto STAGE_A = [&](int t, int slot) {
    const short* at = asrc + t * 64;
    char* l = (char*)lds + slot * 32768;
#pragma unroll
    for (int i = 0; i < 4; ++i) gload_lds16(at + srcA[i], l + (i * 512 + tid) * 16);
  };
  auto STAGE_B = [&](int t, int slot) {
    const short* bt = bsrc + t * 64;
    char* l = (char*)lds + 98304 + slot * 24576;
#pragma unroll
    for (int i = 0; i < 3; ++i) gload_lds16(bt + srcB[i], l + (i * 512 + tid) * 16);
  };

  auto COMPUTE = [&](int i) {
    const char* ab = (const char*)lds + (i % 3) * 32768;
    const char* bb = (const char*)lds + 98304 + (i & 1) * 24576;
    s16x8 bfr[3][2], afr[4][2];
#pragma unroll
    for (int n = 0; n < 3; ++n) {
      bfr[n][0] = *(const s16x8*)(bb + boff[n]);
      bfr[n][1] = *(const s16x8*)(bb + (boff[n] ^ 64));
    }
#pragma unroll
    for (int m = 0; m < 4; ++m) {
      afr[m][0] = *(const s16x8*)(ab + aoff[m]);
      afr[m][1] = *(const s16x8*)(ab + (aoff[m] ^ 64));
    }
    asm volatile("s_waitcnt lgkmcnt(0)" ::: "memory");
    __builtin_amdgcn_sched_barrier(0);
    __builtin_amdgcn_s_setprio(1);
#pragma unroll
    for (int m = 0; m < 4; ++m)
#pragma unroll
      for (int n = 0; n < 3; ++n) {
        acc[m][n] = MFMA16(afr[m][0], bfr[n][0], acc[m][n], 0, 0, 0);
        acc[m][n] = MFMA16(afr[m][1], bfr[n][1], acc[m][n], 0, 0, 0);
      }
    __builtin_amdgcn_s_setprio(0);
#pragma unroll
    for (int m = 0; m < 4; ++m) {
      afr[m][0] = *(const s16x8*)(ab + aoff[m + 4]);
      afr[m][1] = *(const s16x8*)(ab + (aoff[m + 4] ^ 64));
    }
    asm volatile("s_waitcnt lgkmcnt(0)" ::: "memory");
    __builtin_amdgcn_sched_barrier(0);
    __builtin_amdgcn_s_setprio(1);
#pragma unroll
    for (int m = 0; m < 4; ++m)
#pragma unroll
      for (int n = 0; n < 3; ++n) {
        acc[m + 4][n] = MFMA16(afr[m][0], bfr[n][0], acc[m + 4][n], 0, 0, 0);
        acc[m + 4][n] = MFMA16(afr[m][1], bfr[n][1], acc[m + 4][n], 0, 0, 0);
      }
    __builtin_amdgcn_s_setprio(0);
  };

  // prologue: B(0), A(0), A(1)  (A(1) last => newest 4 for the vmcnt(4) ledger)
  STAGE_B(0, 0);
  STAGE_A(0, 0);
  STAGE_A(1, 1);

  for (int i = 0; i < 15; ++i) {
    asm volatile("s_waitcnt vmcnt(4)" ::: "memory");
    __builtin_amdgcn_s_barrier();
    asm volatile("" ::: "memory");
    STAGE_B(i + 1, (i + 1) & 1);
    if (i < 14) STAGE_A(i + 2, (i + 2) % 3);
    COMPUTE(i);
  }
  asm volatile("s_waitcnt vmcnt(0)" ::: "memory");
  __builtin_amdgcn_s_barrier();
  asm volatile("" ::: "memory");
  COMPUTE(15);

  // epilogue: bias + bf16 store into fused C (row stride 3072)
  int nbase = nt * 192 + wn * 48;
  int mbase = mt * 256 + wm * 128;
#pragma unroll
  for (int n = 0; n < 3; ++n) {
    int col = nbase + n * 16 + (lane & 15);
    float bv = bias3[col];
#pragma unroll
    for (int m = 0; m < 8; ++m)
#pragma unroll
      for (int r = 0; r < 4; ++r) {
        int mm = mbase + m * 16 + ((lane >> 4) << 2) + r;
        C[(size_t)mm * 3072 + col] = f2bf(acc[m][n][r] + bv);
      }
  }
}

// ---------------- Kernel 4: block-local attention (round-3 structure, stride 3072) ----
__global__ __launch_bounds__(512) void k_attn(const short* __restrict__ QKV,
                                              const int* __restrict__ perm,
                                              float* __restrict__ out) {
  __shared__ short Qs[256 * 64];
  __shared__ short Ks[256 * 64];
  __shared__ short Vs[64 * 256];
  __shared__ short Ps[8 * 1024];

  int tid = threadIdx.x;
  int lane = tid & 63, wv = tid >> 6;
  int bx = blockIdx.x;
  int b = bx >> 8, g = (bx >> 4) & 15, n = bx & 15;
  int p = perm[g * 16 + n];
  int pg = p >> 4, ph = p & 15;

  const short* qsrc = QKV + (size_t)(b * 4096 + g * 256) * 3072 + n * 64;
  const short* ksrc = QKV + (size_t)(b * 4096 + pg * 256) * 3072 + 1024 + ph * 64;
  const short* vsrc = QKV + (size_t)(b * 4096 + pg * 256) * 3072 + 2048 + ph * 64;

  s16x8 vreg[4];
#pragma unroll
  for (int i = 0; i < 4; ++i) {
    int c = i * 512 + tid;
    int t = c >> 3;
    int d0 = (c & 7) << 3;
    vreg[i] = *(const s16x8*)(vsrc + t * 3072 + d0);
  }
#pragma unroll
  for (int i = 0; i < 4; ++i) {
    int c = i * 512 + tid;
    int row = c >> 3;
    int colb = (c & 7) << 4;
    int sc = colb ^ ((row & 7) << 4);
    gload_lds16(qsrc + row * 3072 + (sc >> 1), (char*)Qs + c * 16);
    gload_lds16(ksrc + row * 3072 + (sc >> 1), (char*)Ks + c * 16);
  }
#pragma unroll
  for (int i = 0; i < 4; ++i) {
    int c = i * 512 + tid;
    int t = c >> 3;
    int d0 = (c & 7) << 3;
#pragma unroll
    for (int j = 0; j < 8; ++j) {
      int d = d0 + j;
      int sl = (d & 7) ^ ((d >> 3) & 7);
      int by = d * 512 + ((t * 2) ^ (sl << 4));
      *(short*)((char*)Vs + by) = vreg[i][j];
    }
  }
  __syncthreads();

  int qr0 = wv * 32;
  f32x4 accS[2][16] = {};
#pragma unroll
  for (int ks = 0; ks < 2; ++ks) {
    int cb = (ks << 6) + ((lane >> 4) << 4);
    s16x8 aq[2];
#pragma unroll
    for (int rf = 0; rf < 2; ++rf) {
      int row = qr0 + rf * 16 + (lane & 15);
      aq[rf] = *(const s16x8*)((const char*)Qs + row * 128 + (cb ^ ((row & 7) << 4)));
    }
#pragma unroll
    for (int cf = 0; cf < 16; ++cf) {
      int row = cf * 16 + (lane & 15);
      s16x8 bk = *(const s16x8*)((const char*)Ks + row * 128 + (cb ^ ((row & 7) << 4)));
      accS[0][cf] = MFMA16(aq[0], bk, accS[0][cf], 0, 0, 0);
      accS[1][cf] = MFMA16(aq[1], bk, accS[1][cf], 0, 0, 0);
    }
  }

  const float sc_log2e = 0.125f * 1.44269504088896f;
  float mx[2][4], inv[2][4];
#pragma unroll
  for (int rf = 0; rf < 2; ++rf)
#pragma unroll
    for (int r = 0; r < 4; ++r) {
      float m_ = accS[rf][0][r];
#pragma unroll
      for (int cf = 1; cf < 16; ++cf) m_ = fmaxf(m_, accS[rf][cf][r]);
#pragma unroll
      for (int msk = 1; msk < 16; msk <<= 1) m_ = fmaxf(m_, __shfl_xor(m_, msk));
      mx[rf][r] = m_;
    }
#pragma unroll
  for (int rf = 0; rf < 2; ++rf)
#pragma unroll
    for (int r = 0; r < 4; ++r) {
      float s_ = 0.f;
#pragma unroll
      for (int cf = 0; cf < 16; ++cf) {
        float e = exp2f((accS[rf][cf][r] - mx[rf][r]) * sc_log2e);
        accS[rf][cf][r] = e;
        s_ += e;
      }
#pragma unroll
      for (int msk = 1; msk < 16; msk <<= 1) s_ += __shfl_xor(s_, msk);
      inv[rf][r] = 1.0f / s_;
    }

  f32x4 accO[2][4] = {};
  short* pchunk = Ps + wv * 1024;
#pragma unroll
  for (int ks = 0; ks < 8; ++ks) {
#pragma unroll
    for (int rf = 0; rf < 2; ++rf)
#pragma unroll
      for (int half = 0; half < 2; ++half) {
        int cf = ks * 2 + half;
        int kvl = half * 16 + (lane & 15);
        int qp = (lane >> 4) << 2;
        int base = rf * 512 + ((kvl >> 3) << 7) + (kvl & 7);
#pragma unroll
        for (int r = 0; r < 4; ++r)
          pchunk[base + (qp + r) * 8] = f2bf(accS[rf][cf][r]);
      }
    int cbv = (ks << 6) + ((lane >> 4) << 4);
#pragma unroll
    for (int rf = 0; rf < 2; ++rf) {
      s16x8 ap = *(const s16x8*)(pchunk + rf * 512 + lane * 8);
#pragma unroll
      for (int dc = 0; dc < 4; ++dc) {
        int vrow = dc * 16 + (lane & 15);
        int sl = (vrow & 7) ^ ((vrow >> 3) & 7);
        s16x8 bv = *(const s16x8*)((const char*)Vs + vrow * 512 + (cbv ^ (sl << 4)));
        accO[rf][dc] = MFMA16(ap, bv, accO[rf][dc], 0, 0, 0);
      }
    }
  }

#pragma unroll
  for (int rf = 0; rf < 2; ++rf)
#pragma unroll
    for (int dc = 0; dc < 4; ++dc)
#pragma unroll
      for (int r = 0; r < 4; ++r) {
        int q = qr0 + rf * 16 + ((lane >> 4) << 2) + r;
        int d = dc * 16 + (lane & 15);
        out[(size_t)((b * 4096 + g * 256 + q) * 16 + n) * 64 + d] = accO[rf][dc][r] * inv[rf][r];
      }
}

extern "C" void kernel_launch(void* const* d_in, const int* in_sizes, int n_in,
                              void* d_out, int out_size, void* d_ws, size_t ws_size,
                              hipStream_t stream) {
  const float* x    = (const float*)d_in[0];
  const int*   perm = (const int*)d_in[2];
  const float* qw   = (const float*)d_in[3];
  const float* qb   = (const float*)d_in[4];
  const float* kw   = (const float*)d_in[5];
  const float* kb   = (const float*)d_in[6];
  const float* vw   = (const float*)d_in[7];
  const float* vb   = (const float*)d_in[8];
  float* out = (float*)d_out;

  char* ws = (char*)d_ws;
  short* Xb    = (short*)(ws);                   // 16 MB [8192][1024] bf16
  short* Wt    = (short*)(ws + 16777216UL);      //  6 MB [3072 n][1024 k] bf16
  short* C     = (short*)(ws + 23068672UL);      // 48 MB [8192][3072] bf16 (Q|K|V fused)
  float* bias3 = (float*)(ws + 73400320UL);      // 12 KB [3072] f32

  hipMemcpyAsync(bias3,        qb, 4096, hipMemcpyDeviceToDevice, stream);
  hipMemcpyAsync(bias3 + 1024, kb, 4096, hipMemcpyDeviceToDevice, stream);
  hipMemcpyAsync(bias3 + 2048, vb, 4096, hipMemcpyDeviceToDevice, stream);

  k_convert_x<<<4096, 256, 0, stream>>>(x, Xb);
  k_transpose_w<<<768, 256, 0, stream>>>(qw, kw, vw, Wt);
  k_gemm<<<512, 512, 0, stream>>>(Xb, Wt, bias3, C);
  k_attn<<<512, 512, 0, stream>>>(C, perm, out);
}